// Round 6
// baseline (161.284 us; speedup 1.0000x reference)
//
#include <hip/hip_runtime.h>

// AreaAttention (pykt), B=8,H=8,L=512,D=64, W=3, d_k=64, zero_pad=1, causal tril.
// Window scores are running means of base scores s_j=(q.k_j)/8; output is
// sum_t coeff[t]*v[t] with coeff a local scatter of softmax probs; causal
// mask == (window end <= q). Mask input (64 MB) never read.
// R5 (resubmit; round 5 failed on infra, not kernel): barrier-free single-wave
// blocks. prep kernel makes bf16 Q(/8), K, V^T in d_ws; main kernel = 2048
// blocks x 64 threads, one wave owns 16 q-rows, K/V fragments load straight
// from global (L2-resident), LDS is wave-private (Ss score exchange + Ps coeff
// tile), zero __syncthreads.

#define LSEQ 512
#define DDIM 64
#define BK 64
#define SPB 88   // Ps row stride (shorts): 176B, bank step 12, 16B-aligned
#define SSW 68   // Ss row stride (floats)

typedef __attribute__((ext_vector_type(8))) short bf8_t;   // 8 bf16 (4 VGPR)
typedef __attribute__((ext_vector_type(4))) float f32x4;

__device__ __forceinline__ unsigned short f2bf(float f) {  // RNE f32->bf16 bits
  union { float f; unsigned u; } v; v.f = f;
  unsigned u = v.u;
  unsigned r = u + 0x7fffu + ((u >> 16) & 1u);
  return (unsigned short)(r >> 16);
}
__device__ __forceinline__ float bf2f(unsigned short h) {
  union { unsigned u; float f; } v; v.u = ((unsigned)h) << 16; return v.f;
}
__device__ __forceinline__ unsigned pk2(float a, float b) {
  return (unsigned)f2bf(a) | ((unsigned)f2bf(b) << 16);
}
__device__ __forceinline__ float ex2(float x) {  // 1-instr exp2
  float r; asm("v_exp_f32 %0, %1" : "=v"(r) : "v"(x)); return r;
}

// ---- prep: bf16 conversions into d_ws + row0 output.
// bid 0..511: V^T[bh][d][t]; 512..1023: Qbf = Q/8; 1024..1535: Kbf; 1536..1599: row0.
__global__ __launch_bounds__(256)
void prep_kernel(const float* __restrict__ qg, const float* __restrict__ kg,
                 const float* __restrict__ vg,
                 unsigned short* __restrict__ vt,
                 unsigned short* __restrict__ qbf,
                 unsigned short* __restrict__ kbf,
                 float* __restrict__ outg) {
  const int bid = blockIdx.x, tid = threadIdx.x;
  if (bid < 512) {               // V transpose -> bf16 [bh][d][t]
    const int bh = bid >> 3, oct = bid & 7;
    const float* vb = vg + (size_t)bh * LSEQ * DDIM;
    unsigned short* vo = vt + (size_t)bh * DDIM * LSEQ;
#pragma unroll
    for (int it = 0; it < 4; ++it) {
      int item = tid + it * 256;       // 1024 items: 64 d x 16 tq
      int d = item & 63, tq = item >> 6;
      int t = oct * 64 + tq * 4;
      ushort4 o;
      o.x = f2bf(vb[(t + 0) * DDIM + d]);
      o.y = f2bf(vb[(t + 1) * DDIM + d]);
      o.z = f2bf(vb[(t + 2) * DDIM + d]);
      o.w = f2bf(vb[(t + 3) * DDIM + d]);
      *(ushort4*)&vo[(size_t)d * LSEQ + t] = o;
    }
  } else if (bid < 1536) {       // straight convert q (scaled 1/8) or k
    const bool isq = bid < 1024;
    const float4* src = (const float4*)(isq ? qg : kg);
    ushort4* dst = (ushort4*)(isq ? qbf : kbf);
    const float s = isq ? 0.125f : 1.0f;
    const int blk = bid & 511;
#pragma unroll
    for (int it = 0; it < 4; ++it) {
      int f = blk * 1024 + it * 256 + tid;   // 524288 float4s per tensor
      float4 x = src[f];
      ushort4 o;
      o.x = f2bf(x.x * s); o.y = f2bf(x.y * s);
      o.z = f2bf(x.z * s); o.w = f2bf(x.w * s);
      dst[f] = o;
    }
  } else {                       // row0: q=0 fully masked -> uniform over 1533
    __shared__ float4 red[256];
    const int bh = bid - 1536;
    const float4* vb4 = (const float4*)(vg + (size_t)bh * LSEQ * DDIM);
    const int d4 = tid & 15, rg = tid >> 4;
    float4 acc = make_float4(0.f, 0.f, 0.f, 0.f);
    for (int t = rg; t < LSEQ; t += 16) {
      float c = (t == 0 || t == LSEQ - 1) ? 3.f
              : (t == 1 || t == LSEQ - 2) ? 5.f : 6.f;
      float4 x = vb4[t * 16 + d4];
      acc.x += c * x.x; acc.y += c * x.y; acc.z += c * x.z; acc.w += c * x.w;
    }
    red[rg * 16 + d4] = acc;
    __syncthreads();
    if (rg == 0) {
      float4 sum = make_float4(0.f, 0.f, 0.f, 0.f);
#pragma unroll
      for (int g = 0; g < 16; ++g) {
        float4 x = red[g * 16 + d4];
        sum.x += x.x; sum.y += x.y; sum.z += x.z; sum.w += x.w;
      }
      const float inv = 1.0f / 1533.0f;
      sum.x *= inv; sum.y *= inv; sum.z *= inv; sum.w *= inv;
      ((float4*)(outg + (size_t)bh * LSEQ * DDIM))[d4] = sum;
    }
  }
}

// ---- main: one wave per (bh, 16-q-row tile). No __syncthreads anywhere;
// all LDS is wave-private (same-wave ds ordering via compiler lgkmcnt waits).
__global__ __launch_bounds__(64, 4)
void area_attn_kernel(const unsigned short* __restrict__ qbf,
                      const unsigned short* __restrict__ kbf,
                      const unsigned short* __restrict__ vtg,
                      float* __restrict__ outg) {
  __shared__ __align__(16) float Ss[16][SSW];        // [q][e], 64,65 = s ctx
  __shared__ __align__(16) unsigned short Ps[16 * SPB];  // coeff [q][t], 64,65 ctx

  const int bid = blockIdx.x;
  const int bh = bid >> 5, qt = bid & 31;
  const int q0 = qt * 16;
  const int lane = threadIdx.x;               // 0..63 (single wave)
  const int lc = lane & 15, lg = lane >> 4;   // frag col/row, k-group
  const int koff = lg * 8;
  const int pr = lane >> 2, ps = lane & 3;    // softmax: row pr(0..15), sub ps
  const int ec0 = ps * 16;
  const float L2E = 1.44269504088896341f;

  const unsigned short* qb = qbf + (size_t)bh * LSEQ * DDIM;
  const unsigned short* kb = kbf + (size_t)bh * LSEQ * DDIM;
  const unsigned short* vtb = vtg + (size_t)bh * DDIM * LSEQ;

  // Q A-fragments (already scaled by 1/8 in prep): row = lane&15, k = koff..
  const bf8_t qa0 = *(const bf8_t*)&qb[(size_t)(q0 + lc) * DDIM + koff];
  const bf8_t qa1 = *(const bf8_t*)&qb[(size_t)(q0 + lc) * DDIM + 32 + koff];

  f32x4 oacc[4];
#pragma unroll
  for (int nt = 0; nt < 4; ++nt) oacc[nt] = (f32x4){0.f, 0.f, 0.f, 0.f};
  float m_run = -3.0e38f, l_run = 0.f;  // log2 domain
  float alphav = 0.f;

  const int ntiles = (qt >> 2) + 1;     // keys 0..64*ntiles-1 cover q0+15
  for (int kt = 0; kt < ntiles; ++kt) {
    const int t0 = kt * BK;

    // s-context carry (raw scores from prev tile's cols 62,63)
    if (ps == 0) {
      if (kt == 0) { Ss[pr][64] = -1.0e30f; Ss[pr][65] = -1.0e30f; }
      else         { Ss[pr][64] = Ss[pr][62]; Ss[pr][65] = Ss[pr][63]; }
    }

    // ---- S = (Q/8) K^T via MFMA, K B-frags straight from global (L2) ----
#pragma unroll
    for (int nt = 0; nt < 4; ++nt) {
      const size_t kr = (size_t)(t0 + nt * 16 + lc) * DDIM;
      bf8_t kf0 = *(const bf8_t*)&kb[kr + koff];
      bf8_t kf1 = *(const bf8_t*)&kb[kr + 32 + koff];
      f32x4 acc = (f32x4){0.f, 0.f, 0.f, 0.f};
      acc = __builtin_amdgcn_mfma_f32_16x16x32_bf16(qa0, kf0, acc, 0, 0, 0);
      acc = __builtin_amdgcn_mfma_f32_16x16x32_bf16(qa1, kf1, acc, 0, 0, 0);
#pragma unroll
      for (int r = 0; r < 4; ++r)
        Ss[4 * lg + r][nt * 16 + lc] = acc[r];
    }

    // ---- online softmax over 3 derived window scores per key ----
    {
      const int vmax = q0 + pr - t0;   // valid: ec <= vmax (always >= 0)
      float pm1, pm2;
      if (ps == 0) { pm1 = Ss[pr][65] * L2E; pm2 = Ss[pr][64] * L2E; }
      else         { pm1 = Ss[pr][ec0 - 1] * L2E; pm2 = Ss[pr][ec0 - 2] * L2E; }

      float sv[16];
      *(float4*)&sv[0]  = *(const float4*)&Ss[pr][ec0];
      *(float4*)&sv[4]  = *(const float4*)&Ss[pr][ec0 + 4];
      *(float4*)&sv[8]  = *(const float4*)&Ss[pr][ec0 + 8];
      *(float4*)&sv[12] = *(const float4*)&Ss[pr][ec0 + 12];
#pragma unroll
      for (int k = 0; k < 16; ++k) sv[k] *= L2E;

      float mloc = -3.0e38f;
      {
        float a1 = pm1, a2 = pm2;
#pragma unroll
        for (int k = 0; k < 16; ++k) {
          float s0 = sv[k];
          float t = a1 + s0;
          float mm = fmaxf(s0, fmaxf(0.5f * t, (1.0f / 3.0f) * (a2 + t)));
          if (ec0 + k <= vmax) mloc = fmaxf(mloc, mm);
          a2 = a1; a1 = s0;
        }
      }
      mloc = fmaxf(mloc, __shfl_xor(mloc, 1));
      mloc = fmaxf(mloc, __shfl_xor(mloc, 2));
      const float m_new = fmaxf(m_run, mloc);
      alphav = ex2(m_run - m_new);
      m_run = m_new;
      l_run *= alphav;

      float cf[18];
#pragma unroll
      for (int k = 0; k < 18; ++k) cf[k] = 0.f;
      float ladd = 0.f;
      {
        float a1 = pm1, a2 = pm2;
#pragma unroll
        for (int k = 0; k < 16; ++k) {
          float s0 = sv[k];
          bool vld = (ec0 + k) <= vmax;
          float t = a1 + s0;
          float p1 = vld ? ex2(s0 - m_new) : 0.f;
          float p2 = vld ? ex2(0.5f * t - m_new) : 0.f;
          float p3 = vld ? ex2((1.0f / 3.0f) * (a2 + t) - m_new) : 0.f;
          float p23 = p2 + p3, p123 = p1 + p23;
          ladd += p123;
          cf[k + 2] += p123;   // t = e
          cf[k + 1] += p23;    // t = e-1
          cf[k]     += p3;     // t = e-2
          a2 = a1; a1 = s0;
        }
      }
      ladd += __shfl_xor(ladd, 1);
      ladd += __shfl_xor(ladd, 2);
      l_run += ladd;

      // tail overlap -> neighbor's head via register shuffle (1 writer/slot)
      float up16 = __shfl_up(cf[16], 1, 4);
      float up17 = __shfl_up(cf[17], 1, 4);
      if (ps > 0) { cf[0] += up16; cf[1] += up17; }

      // coeff as packed bf16 pairs, row-major [q][t]; ctx at 64,65.
      const int base = pr * SPB;
      if (ps == 0) {
        *(unsigned*)&Ps[base + 64] = pk2(cf[0], cf[1]);   // t0-2, t0-1
#pragma unroll
        for (int j = 0; j < 7; ++j)
          *(unsigned*)&Ps[base + 2 * j] = pk2(cf[2 + 2 * j], cf[3 + 2 * j]);
      } else {
        const int tcb = 16 * ps - 2;
#pragma unroll
        for (int j = 0; j < 8; ++j)
          *(unsigned*)&Ps[base + tcb + 2 * j] = pk2(cf[2 * j], cf[2 * j + 1]);
        if (ps == 3) *(unsigned*)&Ps[base + 62] = pk2(cf[16], cf[17]);
      }
    }

    // ---- O = O*alpha + coeff x V via MFMA, V^T B-frags from global ----
    {
      float av[4];
#pragma unroll
      for (int r = 0; r < 4; ++r) av[r] = __shfl(alphav, 16 * lg + 4 * r);
#pragma unroll
      for (int nt = 0; nt < 4; ++nt)
#pragma unroll
        for (int r = 0; r < 4; ++r) oacc[nt][r] *= av[r];

      bf8_t pa0 = *(const bf8_t*)&Ps[lc * SPB + koff];
      bf8_t pa1 = *(const bf8_t*)&Ps[lc * SPB + 32 + koff];
      float cm2[4], cm1[4];
#pragma unroll
      for (int r = 0; r < 4; ++r) {
        unsigned pc = *(const unsigned*)&Ps[(4 * lg + r) * SPB + 64];
        cm2[r] = bf2f((unsigned short)(pc & 0xffffu));
        cm1[r] = bf2f((unsigned short)(pc >> 16));
      }
#pragma unroll
      for (int nt = 0; nt < 4; ++nt) {
        const size_t vr = (size_t)(nt * 16 + lc) * LSEQ + t0;
        bf8_t vf0 = *(const bf8_t*)&vtb[vr + koff];
        bf8_t vf1 = *(const bf8_t*)&vtb[vr + 32 + koff];
        oacc[nt] = __builtin_amdgcn_mfma_f32_16x16x32_bf16(pa0, vf0, oacc[nt], 0, 0, 0);
        oacc[nt] = __builtin_amdgcn_mfma_f32_16x16x32_bf16(pa1, vf1, oacc[nt], 0, 0, 0);
        unsigned vc = 0;
        if (kt > 0) vc = *(const unsigned*)&vtb[vr - 2];
        float vm2 = bf2f((unsigned short)(vc & 0xffffu));
        float vm1 = bf2f((unsigned short)(vc >> 16));
#pragma unroll
        for (int r = 0; r < 4; ++r)
          oacc[nt][r] += cm2[r] * vm2 + cm1[r] * vm1;
      }
    }
  }

  // ---- epilogue: divide by denom (shfl-broadcast), store; skip row 0 ----
#pragma unroll
  for (int r = 0; r < 4; ++r) {
    float lr = __shfl(l_run, 16 * lg + 4 * r);
    int gr = q0 + 4 * lg + r;
    if (gr != 0) {
      float inv = 1.0f / lr;
#pragma unroll
      for (int nt = 0; nt < 4; ++nt)
        outg[(size_t)(bh * LSEQ + gr) * DDIM + nt * 16 + lc] = oacc[nt][r] * inv;
    }
  }
}

extern "C" void kernel_launch(void* const* d_in, const int* in_sizes, int n_in,
                              void* d_out, int out_size, void* d_ws, size_t ws_size,
                              hipStream_t stream) {
  (void)in_sizes; (void)n_in; (void)ws_size; (void)out_size;
  const float* q = (const float*)d_in[0];
  const float* k = (const float*)d_in[1];
  const float* v = (const float*)d_in[2];
  float* out = (float*)d_out;

  unsigned short* ws = (unsigned short*)d_ws;   // 3 x 2,097,152 bf16 = 12 MB
  unsigned short* vt  = ws;
  unsigned short* qbf = ws + 2097152;
  unsigned short* kbf = ws + 2 * 2097152;

  prep_kernel<<<dim3(1600), dim3(256), 0, stream>>>(q, k, v, vt, qbf, kbf, out);
  area_attn_kernel<<<dim3(2048), dim3(64), 0, stream>>>(qbf, kbf, vt, out);
}